// Round 1
// baseline (654.651 us; speedup 1.0000x reference)
//
#include <hip/hip_runtime.h>
#include <hip/hip_bf16.h>
#include <stdint.h>

// B=1, S=2048, D=4096, H=32, HD=128
// Pipeline: cast -> QKV GEMM (bf16 mfma) -> RoPE -> V-transpose -> flash attn -> out GEMM

typedef __attribute__((ext_vector_type(8))) short bf16x8;
typedef __attribute__((ext_vector_type(4))) float f32x4;

#define S_LEN 2048
#define DMODEL 4096
#define NHEAD 32
#define HDIM 128
#define QKV_LD 12288  // row stride of fused qkv output

// ---------------- helpers ----------------
__device__ __forceinline__ unsigned short f2bf(float f) {
  unsigned int u = __float_as_uint(f);
  unsigned int r = u + 0x7FFFu + ((u >> 16) & 1u);  // RNE
  return (unsigned short)(r >> 16);
}
__device__ __forceinline__ float bf2f(unsigned short h) {
  return __uint_as_float(((unsigned int)h) << 16);
}
__device__ __forceinline__ void gl_lds16(const void* g, void* l) {
  // async global->LDS, 16B per lane; LDS dest = wave-uniform base + lane*16
  __builtin_amdgcn_global_load_lds((const __attribute__((address_space(1))) unsigned int*)g,
                                   (__attribute__((address_space(3))) unsigned int*)l, 16, 0, 0);
}

// ---------------- cast fp32 -> bf16 (vectorized) ----------------
__global__ __launch_bounds__(256) void cast_f32_bf16(const float* __restrict__ src,
                                                     unsigned short* __restrict__ dst, int n4) {
  int i = blockIdx.x * blockDim.x + threadIdx.x;
  int stride = gridDim.x * blockDim.x;
  for (; i < n4; i += stride) {
    float4 v = ((const float4*)src)[i];
    ushort4 o;
    o.x = f2bf(v.x); o.y = f2bf(v.y); o.z = f2bf(v.z); o.w = f2bf(v.w);
    ((ushort4*)dst)[i] = o;
  }
}

// ---------------- rope cos/sin table: cs[s][2i]=cos, [2i+1]=sin ----------------
__global__ __launch_bounds__(256) void rope_table(const float* __restrict__ freqs,
                                                  float* __restrict__ cs) {
  int i = blockIdx.x * blockDim.x + threadIdx.x;  // S * 64
  if (i < S_LEN * 64) {
    float f = freqs[i];
    cs[2 * i]     = cosf(f);
    cs[2 * i + 1] = sinf(f);
  }
}

// ---------------- m97-style GEMM: C[M,N] = A[M,K] * B[N,K]^T, bf16 in ----------------
// 128x128 tile, BK=32, 4 waves each 64x64, global_load_lds staging with XOR chunk swizzle
template <bool OUT_BF16>
__global__ __launch_bounds__(256) void gemm_bt(const unsigned short* __restrict__ A,
                                               const unsigned short* __restrict__ B,
                                               void* __restrict__ C, int M, int N, int K) {
  __shared__ __align__(16) unsigned short Abuf[128 * 32];
  __shared__ __align__(16) unsigned short Bbuf[128 * 32];
  const int tid = threadIdx.x;
  const int lane = tid & 63;
  const int w = tid >> 6;
  const int wm = w >> 1, wn = w & 1;
  const int bm = blockIdx.y, bn = blockIdx.x;
  const int l15 = lane & 15, l4 = lane >> 4;

  f32x4 acc[4][4] = {};
  const int nk = K >> 5;
  for (int kk = 0; kk < nk; ++kk) {
    __syncthreads();
#pragma unroll
    for (int i = 0; i < 2; ++i) {
      int b = (w * 2 + i) * 64 + lane;
      int r = b >> 2, c = b & 3;
      int csw = c ^ (r & 3);  // pre-swizzle source so swizzled read is conflict-reduced
      gl_lds16(A + (size_t)(bm * 128 + r) * K + kk * 32 + csw * 8, &Abuf[(w * 2 + i) * 512]);
    }
#pragma unroll
    for (int i = 0; i < 2; ++i) {
      int b = (w * 2 + i) * 64 + lane;
      int r = b >> 2, c = b & 3;
      int csw = c ^ (r & 3);
      gl_lds16(B + (size_t)(bn * 128 + r) * K + kk * 32 + csw * 8, &Bbuf[(w * 2 + i) * 512]);
    }
    __syncthreads();

    bf16x8 a[4], bfr[4];
#pragma unroll
    for (int mt = 0; mt < 4; ++mt) {
      int r = wm * 64 + mt * 16 + l15;
      a[mt] = *(const bf16x8*)&Abuf[r * 32 + ((l4 ^ (r & 3)) * 8)];
    }
#pragma unroll
    for (int nt = 0; nt < 4; ++nt) {
      int r = wn * 64 + nt * 16 + l15;
      bfr[nt] = *(const bf16x8*)&Bbuf[r * 32 + ((l4 ^ (r & 3)) * 8)];
    }
#pragma unroll
    for (int mt = 0; mt < 4; ++mt)
#pragma unroll
      for (int nt = 0; nt < 4; ++nt)
        acc[mt][nt] = __builtin_amdgcn_mfma_f32_16x16x32_bf16(a[mt], bfr[nt], acc[mt][nt], 0, 0, 0);
  }

#pragma unroll
  for (int mt = 0; mt < 4; ++mt)
#pragma unroll
    for (int nt = 0; nt < 4; ++nt) {
      int row = bm * 128 + wm * 64 + mt * 16 + l4 * 4;
      int col = bn * 128 + wn * 64 + nt * 16 + l15;
      if (OUT_BF16) {
        unsigned short* Cp = (unsigned short*)C;
#pragma unroll
        for (int r = 0; r < 4; ++r) Cp[(size_t)(row + r) * N + col] = f2bf(acc[mt][nt][r]);
      } else {
        float* Cp = (float*)C;
#pragma unroll
        for (int r = 0; r < 4; ++r) Cp[(size_t)(row + r) * N + col] = acc[mt][nt][r];
      }
    }
}

// ---------------- RoPE in-place on qkv cols [0, 8192) ----------------
__global__ __launch_bounds__(256) void rope_apply(unsigned short* __restrict__ qkv,
                                                  const float* __restrict__ cs) {
  int t = blockIdx.x * blockDim.x + threadIdx.x;  // S * 8192 / 8
  if (t >= S_LEN * 1024) return;
  int row = t >> 10;
  int col = (t & 1023) * 8;
  int d = col & (HDIM - 1);  // position within head (multiple of 8)
  ushort4* p = (ushort4*)(qkv + (size_t)row * QKV_LD + col);
  ushort4 v0 = p[0], v1 = p[1];
  float4 c0 = *(const float4*)&cs[row * HDIM + d];
  float4 c1 = *(const float4*)&cs[row * HDIM + d + 4];
  ushort4 o0, o1;
  {
    float t0 = bf2f(v0.x), t1 = bf2f(v0.y);
    o0.x = f2bf(t0 * c0.x - t1 * c0.y);
    o0.y = f2bf(t0 * c0.y + t1 * c0.x);
    t0 = bf2f(v0.z); t1 = bf2f(v0.w);
    o0.z = f2bf(t0 * c0.z - t1 * c0.w);
    o0.w = f2bf(t0 * c0.w + t1 * c0.z);
    t0 = bf2f(v1.x); t1 = bf2f(v1.y);
    o1.x = f2bf(t0 * c1.x - t1 * c1.y);
    o1.y = f2bf(t0 * c1.y + t1 * c1.x);
    t0 = bf2f(v1.z); t1 = bf2f(v1.w);
    o1.z = f2bf(t0 * c1.z - t1 * c1.w);
    o1.w = f2bf(t0 * c1.w + t1 * c1.z);
  }
  p[0] = o0; p[1] = o1;
}

// ---------------- V transpose: qkv cols [8192,12288) -> vt[h][d][s] ----------------
__global__ __launch_bounds__(256) void v_transpose(const unsigned short* __restrict__ qkv,
                                                   unsigned short* __restrict__ vt) {
  __shared__ unsigned short T[64][68];  // [s][d], stride 68 to spread banks
  int sb = blockIdx.x * 64;
  int h = blockIdx.y >> 1;
  int d0 = (blockIdx.y & 1) * 64;
  int tid = threadIdx.x;
#pragma unroll
  for (int i = 0; i < 2; ++i) {
    int b = i * 256 + tid;
    int r = b >> 3, c = b & 7;
    const ushort4* src = (const ushort4*)(qkv + (size_t)(sb + r) * QKV_LD + 8192 + h * HDIM + d0 + c * 8);
    ushort4 a0 = src[0], a1 = src[1];
    *(ushort4*)&T[r][c * 8] = a0;
    *(ushort4*)&T[r][c * 8 + 4] = a1;
  }
  __syncthreads();
#pragma unroll
  for (int i = 0; i < 2; ++i) {
    int b = i * 256 + tid;
    int dd = b >> 3, sc = b & 7;
    unsigned short tmp[8];
#pragma unroll
    for (int j = 0; j < 8; ++j) tmp[j] = T[sc * 8 + j][dd];
    unsigned short* dst = vt + (size_t)(h * HDIM + d0 + dd) * S_LEN + sb + sc * 8;
    ushort4 lo = make_ushort4(tmp[0], tmp[1], tmp[2], tmp[3]);
    ushort4 hi = make_ushort4(tmp[4], tmp[5], tmp[6], tmp[7]);
    *(ushort4*)dst = lo;
    *(ushort4*)(dst + 4) = hi;
  }
}

// ---------------- flash attention (causal), 4 waves x 16 q-rows, KVBLK=64 ----------------
__global__ __launch_bounds__(256) void attn_kernel(const unsigned short* __restrict__ qkv,
                                                   const unsigned short* __restrict__ vt,
                                                   unsigned short* __restrict__ out) {
  __shared__ __align__(16) unsigned short Klds[64 * 128];   // [kv][d], chunk-swizzled ^(r&15)
  __shared__ __align__(16) unsigned short Vtlds[128 * 64];  // [d][kv], chunk-swizzled ^(r&7)
  __shared__ __align__(16) unsigned short Plds[4][16 * 72]; // per-wave P, row stride 72
  const int tid = threadIdx.x, lane = tid & 63, w = tid >> 6;
  const int l15 = lane & 15, l4 = lane >> 4;
  const int h = blockIdx.y, bq = blockIdx.x;
  const int qw = bq * 64 + w * 16;

  // Q fragments (roped) straight from global
  bf16x8 qf[4];
#pragma unroll
  for (int ds = 0; ds < 4; ++ds)
    qf[ds] = *(const bf16x8*)&qkv[(size_t)(qw + l15) * QKV_LD + h * HDIM + ds * 32 + l4 * 8];

  f32x4 acc[8] = {};
  float m_run[4], l_run[4];
#pragma unroll
  for (int r = 0; r < 4; ++r) { m_run[r] = -1e30f; l_run[r] = 0.f; }

  const float scale = 0.08838834764831845f;  // 1/sqrt(128)
  const int nkt = bq + 1;
  for (int kt = 0; kt < nkt; ++kt) {
    const int kv0 = kt * 64;
    __syncthreads();
    // stage K tile [64][128] (source pre-swizzled so reads are conflict-free)
#pragma unroll
    for (int i = 0; i < 4; ++i) {
      int b = (w * 4 + i) * 64 + lane;
      int r = b >> 4, c = b & 15;
      gl_lds16(qkv + (size_t)(kv0 + r) * QKV_LD + 4096 + h * HDIM + ((c ^ (r & 15)) * 8),
               &Klds[(w * 4 + i) * 512]);
    }
    // stage Vt tile [128][64]
#pragma unroll
    for (int i = 0; i < 4; ++i) {
      int b = (w * 4 + i) * 64 + lane;
      int r = b >> 3, c = b & 7;
      gl_lds16(vt + (size_t)(h * HDIM + r) * S_LEN + kv0 + ((c ^ (r & 7)) * 8),
               &Vtlds[(w * 4 + i) * 512]);
    }
    __syncthreads();

    // QK^T -> s[jt]: 16 q-rows x 64 kv
    f32x4 s[4] = {};
#pragma unroll
    for (int jt = 0; jt < 4; ++jt) {
      int kr = jt * 16 + l15;
#pragma unroll
      for (int ds = 0; ds < 4; ++ds) {
        int c = (ds * 4 + l4) ^ (kr & 15);
        bf16x8 kf = *(const bf16x8*)&Klds[kr * 128 + c * 8];
        s[jt] = __builtin_amdgcn_mfma_f32_16x16x32_bf16(qf[ds], kf, s[jt], 0, 0, 0);
      }
    }

    const bool diag = (kt == bq);
#pragma unroll
    for (int jt = 0; jt < 4; ++jt)
#pragma unroll
      for (int r = 0; r < 4; ++r) {
        float v = s[jt][r] * scale;
        if (diag) {
          int kvg = kv0 + jt * 16 + l15;
          int qg = qw + l4 * 4 + r;
          if (kvg > qg) v = -1e30f;
        }
        s[jt][r] = v;
      }

    // online softmax (row groups: 16 lanes sharing l4 hold rows l4*4+r)
    float alpha[4];
#pragma unroll
    for (int r = 0; r < 4; ++r) {
      float mx = fmaxf(fmaxf(s[0][r], s[1][r]), fmaxf(s[2][r], s[3][r]));
#pragma unroll
      for (int off = 1; off < 16; off <<= 1) mx = fmaxf(mx, __shfl_xor(mx, off, 64));
      float mi = fmaxf(m_run[r], mx);
      alpha[r] = __expf(m_run[r] - mi);
      m_run[r] = mi;
      float sum = 0.f;
#pragma unroll
      for (int jt = 0; jt < 4; ++jt) {
        float p = __expf(s[jt][r] - mi);
        s[jt][r] = p;
        sum += p;
      }
#pragma unroll
      for (int off = 1; off < 16; off <<= 1) sum += __shfl_xor(sum, off, 64);
      l_run[r] = l_run[r] * alpha[r] + sum;
    }
#pragma unroll
    for (int dt = 0; dt < 8; ++dt)
#pragma unroll
      for (int r = 0; r < 4; ++r) acc[dt][r] *= alpha[r];

    // P (C-layout) -> LDS -> A-layout
    unsigned short* P = &Plds[w][0];
#pragma unroll
    for (int jt = 0; jt < 4; ++jt)
#pragma unroll
      for (int r = 0; r < 4; ++r)
        P[(l4 * 4 + r) * 72 + jt * 16 + l15] = f2bf(s[jt][r]);

    // PV: O(16x128) += P(16x64) @ V(64x128)
#pragma unroll
    for (int ks = 0; ks < 2; ++ks) {
      bf16x8 pa = *(const bf16x8*)&P[l15 * 72 + ks * 32 + l4 * 8];
#pragma unroll
      for (int dt = 0; dt < 8; ++dt) {
        int vr = dt * 16 + l15;
        int c = (ks * 4 + l4) ^ (vr & 7);
        bf16x8 vf = *(const bf16x8*)&Vtlds[vr * 64 + c * 8];
        acc[dt] = __builtin_amdgcn_mfma_f32_16x16x32_bf16(pa, vf, acc[dt], 0, 0, 0);
      }
    }
  }

  // epilogue: out[s][h*128+d] = O / l
#pragma unroll
  for (int dt = 0; dt < 8; ++dt)
#pragma unroll
    for (int r = 0; r < 4; ++r) {
      float v = acc[dt][r] / l_run[r];
      int row = qw + l4 * 4 + r;
      int col = h * HDIM + dt * 16 + l15;
      out[(size_t)row * DMODEL + col] = f2bf(v);
    }
}

// ---------------- launcher ----------------
extern "C" void kernel_launch(void* const* d_in, const int* in_sizes, int n_in,
                              void* d_out, int out_size, void* d_ws, size_t ws_size,
                              hipStream_t stream) {
  const float* x = (const float*)d_in[0];
  const float* fr = (const float*)d_in[1];
  const float* wq = (const float*)d_in[2];
  const float* wk = (const float*)d_in[3];
  const float* wv = (const float*)d_in[4];
  const float* wo = (const float*)d_in[5];

  char* ws = (char*)d_ws;
  const size_t OFF_XB   = 0;                       // 2048*4096*2      = 16 MB
  const size_t OFF_WQKV = 16777216;                // 12288*4096*2     = 96 MB
  const size_t OFF_WO   = OFF_WQKV + 100663296;    // 4096*4096*2      = 32 MB
  const size_t OFF_QKV  = OFF_WO + 33554432;       // 2048*12288*2     = 48 MB
  const size_t OFF_CS   = OFF_QKV + 50331648;      // 2048*128*4       = 1 MB
  const size_t OFF_VT   = OFF_CS + 1048576;        // 32*128*2048*2    = 16 MB
  const size_t OFF_ATTN = OFF_VT + 16777216;       // 2048*4096*2      = 16 MB

  unsigned short* xb    = (unsigned short*)(ws + OFF_XB);
  unsigned short* wqkvb = (unsigned short*)(ws + OFF_WQKV);
  unsigned short* wob   = (unsigned short*)(ws + OFF_WO);
  unsigned short* qkvb  = (unsigned short*)(ws + OFF_QKV);
  float*          cs    = (float*)(ws + OFF_CS);
  unsigned short* vt    = (unsigned short*)(ws + OFF_VT);
  unsigned short* attn  = (unsigned short*)(ws + OFF_ATTN);

  // 1. casts
  cast_f32_bf16<<<2048, 256, 0, stream>>>(x, xb, 2097152);
  cast_f32_bf16<<<2048, 256, 0, stream>>>(wq, wqkvb, 4194304);
  cast_f32_bf16<<<2048, 256, 0, stream>>>(wk, wqkvb + 16777216, 4194304);
  cast_f32_bf16<<<2048, 256, 0, stream>>>(wv, wqkvb + 33554432, 4194304);
  cast_f32_bf16<<<2048, 256, 0, stream>>>(wo, wob, 4194304);
  // 2. rope table
  rope_table<<<512, 256, 0, stream>>>(fr, cs);
  // 3. fused QKV projection
  gemm_bt<true><<<dim3(96, 16), 256, 0, stream>>>(xb, wqkvb, qkvb, 2048, 12288, 4096);
  // 4. RoPE on q,k
  rope_apply<<<8192, 256, 0, stream>>>(qkvb, cs);
  // 5. V transpose
  v_transpose<<<dim3(32, 64), 256, 0, stream>>>(qkvb, vt);
  // 6. flash attention
  attn_kernel<<<dim3(32, 32), 256, 0, stream>>>(qkvb, vt, attn);
  // 7. output projection (fp32 out)
  gemm_bt<false><<<dim3(32, 16), 256, 0, stream>>>(attn, wob, d_out, 2048, 4096, 4096);
}

// Round 2
// 643.305 us; speedup vs baseline: 1.0176x; 1.0176x over previous
//
#include <hip/hip_runtime.h>
#include <hip/hip_bf16.h>
#include <stdint.h>

// B=1, S=2048, D=4096, H=32, HD=128
// Pipeline: cast -> QKV GEMM (256^2 8-phase bf16 mfma) -> RoPE -> V-transpose -> flash attn -> out GEMM

typedef __attribute__((ext_vector_type(8))) short bf16x8;
typedef __attribute__((ext_vector_type(4))) float f32x4;

#define S_LEN 2048
#define DMODEL 4096
#define NHEAD 32
#define HDIM 128
#define QKV_LD 12288  // row stride of fused qkv output

// ---------------- helpers ----------------
__device__ __forceinline__ unsigned short f2bf(float f) {
  unsigned int u = __float_as_uint(f);
  unsigned int r = u + 0x7FFFu + ((u >> 16) & 1u);  // RNE
  return (unsigned short)(r >> 16);
}
__device__ __forceinline__ float bf2f(unsigned short h) {
  return __uint_as_float(((unsigned int)h) << 16);
}
__device__ __forceinline__ void gl_lds16(const void* g, void* l) {
  // async global->LDS, 16B per lane; LDS dest = wave-uniform base + lane*16
  __builtin_amdgcn_global_load_lds((const __attribute__((address_space(1))) unsigned int*)g,
                                   (__attribute__((address_space(3))) unsigned int*)l, 16, 0, 0);
}
__device__ __forceinline__ void fence_barrier() {
  asm volatile("" ::: "memory");
  __builtin_amdgcn_s_barrier();
  asm volatile("" ::: "memory");
}

// ---------------- cast fp32 -> bf16 (vectorized) ----------------
__global__ __launch_bounds__(256) void cast_f32_bf16(const float* __restrict__ src,
                                                     unsigned short* __restrict__ dst, int n4) {
  int i = blockIdx.x * blockDim.x + threadIdx.x;
  int stride = gridDim.x * blockDim.x;
  for (; i < n4; i += stride) {
    float4 v = ((const float4*)src)[i];
    ushort4 o;
    o.x = f2bf(v.x); o.y = f2bf(v.y); o.z = f2bf(v.z); o.w = f2bf(v.w);
    ((ushort4*)dst)[i] = o;
  }
}

// ---------------- rope cos/sin table: cs[s][2i]=cos, [2i+1]=sin ----------------
__global__ __launch_bounds__(256) void rope_table(const float* __restrict__ freqs,
                                                  float* __restrict__ cs) {
  int i = blockIdx.x * blockDim.x + threadIdx.x;  // S * 64
  if (i < S_LEN * 64) {
    float f = freqs[i];
    cs[2 * i]     = cosf(f);
    cs[2 * i + 1] = sinf(f);
  }
}

// ---------------- 256^2 8-phase GEMM: C[M,N] = A[M,K] * B[N,K]^T, bf16 in ----------------
// 8 waves (2M x 4N), per-wave 128x64 output, BK=64, double-buffered 128KiB LDS,
// 1 quarter-tile (8KB) staged per phase, counted vmcnt(6) once per K-tile, setprio
// around 16-MFMA quadrants. XOR swizzle: 16B-chunk ^= (row&7) -> conflict-free b128 reads.
__device__ __forceinline__ void mfma_quad(f32x4 (&acc)[8][4], const bf16x8 (&af)[4][2],
                                          const bf16x8 (&bf)[2][2], int moff, int noff) {
  __builtin_amdgcn_s_setprio(1);
#pragma unroll
  for (int mi = 0; mi < 4; ++mi)
#pragma unroll
    for (int ni = 0; ni < 2; ++ni)
#pragma unroll
      for (int kk = 0; kk < 2; ++kk)
        acc[moff + mi][noff + ni] = __builtin_amdgcn_mfma_f32_16x16x32_bf16(
            af[mi][kk], bf[ni][kk], acc[moff + mi][noff + ni], 0, 0, 0);
  __builtin_amdgcn_s_setprio(0);
}

template <bool OUT_BF16>
__global__ __launch_bounds__(512, 2) void gemm256_8ph(const unsigned short* __restrict__ A,
                                                      const unsigned short* __restrict__ B,
                                                      void* __restrict__ C,
                                                      int M, int N, int K) {
  __shared__ __align__(16) unsigned short Al[2][256 * 64];
  __shared__ __align__(16) unsigned short Bl[2][256 * 64];
  const int tid = threadIdx.x;
  const int lane = tid & 63, wid = tid >> 6;
  const int wr = wid >> 2, wc = wid & 3;
  const int l15 = lane & 15, l4 = lane >> 4;

  const int nbn = N >> 8;
  const int wg = blockIdx.x;  // natural order: nbn%8==0 -> bn-mod-8 XCD affinity
  const int bm = wg / nbn, bn = wg % nbn;

  const int nk = K >> 6;

  // staging: thread tid loads 16B; dest byte (in quarter) = tid*16 -> row=tid>>3, chunk=tid&7
  // pre-swizzled source: chunk ^= row&7 (involution; read applies same XOR)
  const int srow = tid >> 3;
  const int scol = ((tid & 7) ^ (srow & 7)) * 8;
  const unsigned short* Asrc = A + (size_t)(bm * 256 + srow) * K + scol;
  const unsigned short* Bsrc = B + (size_t)(bn * 256 + srow) * K + scol;
  const int ldsdst = wid * 512;  // elements, within quarter

#define STA(b, kt, q) gl_lds16(Asrc + ((size_t)(q) * 64) * K + (kt) * 64, &Al[b][(q) * 4096 + ldsdst])
#define STB(b, kt, q) gl_lds16(Bsrc + ((size_t)(q) * 64) * K + (kt) * 64, &Bl[b][(q) * 4096 + ldsdst])

  const int swz = (l15 & 7) << 4;  // byte XOR on bits 4-6 of the 128B row

  f32x4 acc[8][4] = {};
  bf16x8 afr[4][2], b0fr[2][2], b1fr[2][2];

  // ---- prologue: tile0 full + tile1 {Aq0,Aq2,B all} ----
#pragma unroll
  for (int q = 0; q < 4; ++q) STA(0, 0, q);
#pragma unroll
  for (int q = 0; q < 4; ++q) STB(0, 0, q);
  {
    const int k1 = (nk > 1) ? 1 : 0;
    STA(1, k1, 0); STA(1, k1, 2);
    STB(1, k1, 0); STB(1, k1, 1); STB(1, k1, 2); STB(1, k1, 3);
  }
  asm volatile("s_waitcnt vmcnt(6)" ::: "memory");  // tile0 landed; 3 quarters in flight
  fence_barrier();

  for (int t = 0; t < nk; ++t) {
    const int b = t & 1;
    const char* Ab = (const char*)&Al[b][0];
    const char* Bb = (const char*)&Bl[b][0];
    const int kt1 = (t + 1 < nk) ? (t + 1) : (nk - 1);
    const int kt2 = (t + 2 < nk) ? (t + 2) : (nk - 1);

    // ---------- P1: quadrant (mh0, nh0); reads A mh0 (8) + B nh0 (4) ----------
#pragma unroll
    for (int mi = 0; mi < 4; ++mi) {
      const char* rb = Ab + (wr * 128 + mi * 16 + l15) * 128;
#pragma unroll
      for (int kk = 0; kk < 2; ++kk)
        afr[mi][kk] = *(const bf16x8*)(rb + ((kk * 64 + l4 * 16) ^ swz));
    }
#pragma unroll
    for (int ni = 0; ni < 2; ++ni) {
      const char* rb = Bb + (wc * 64 + ni * 16 + l15) * 128;
#pragma unroll
      for (int kk = 0; kk < 2; ++kk)
        b0fr[ni][kk] = *(const bf16x8*)(rb + ((kk * 64 + l4 * 16) ^ swz));
    }
    STA(b ^ 1, kt1, 1); STA(b ^ 1, kt1, 3);  // complete tile t+1 (A q1,q3)
    fence_barrier();
    mfma_quad(acc, afr, b0fr, 0, 0);
    fence_barrier();

    // ---------- P2: (mh0, nh1); reads B nh1 (4) ----------
#pragma unroll
    for (int ni = 0; ni < 2; ++ni) {
      const char* rb = Bb + (wc * 64 + (2 + ni) * 16 + l15) * 128;
#pragma unroll
      for (int kk = 0; kk < 2; ++kk)
        b1fr[ni][kk] = *(const bf16x8*)(rb + ((kk * 64 + l4 * 16) ^ swz));
    }
    STA(b, kt2, 0); STA(b, kt2, 2);  // A q0,q2 of t+2 (q0,q2 last read at P1)
    fence_barrier();
    mfma_quad(acc, afr, b1fr, 0, 2);
    fence_barrier();

    // ---------- P3: (mh1, nh1); reads A mh1 (8) ----------
#pragma unroll
    for (int mi = 0; mi < 4; ++mi) {
      const char* rb = Ab + (wr * 128 + 64 + mi * 16 + l15) * 128;
#pragma unroll
      for (int kk = 0; kk < 2; ++kk)
        afr[mi][kk] = *(const bf16x8*)(rb + ((kk * 64 + l4 * 16) ^ swz));
    }
    STB(b, kt2, 0); STB(b, kt2, 1);  // B q0,q1 of t+2 (B last read at P2)
    fence_barrier();
    mfma_quad(acc, afr, b1fr, 4, 2);
    fence_barrier();

    // ---------- P4: (mh1, nh0); no reads ----------
    STB(b, kt2, 2); STB(b, kt2, 3);
    asm volatile("s_waitcnt vmcnt(6)" ::: "memory");  // everything <= tP1 landed => tile t+1 ready
    fence_barrier();
    mfma_quad(acc, afr, b0fr, 4, 0);
    fence_barrier();
  }
  asm volatile("s_waitcnt vmcnt(0)" ::: "memory");

  // epilogue
  const size_t crow0 = (size_t)bm * 256 + wr * 128 + l4 * 4;
  const int ccol0 = bn * 256 + wc * 64 + l15;
#pragma unroll
  for (int mf = 0; mf < 8; ++mf)
#pragma unroll
    for (int nf = 0; nf < 4; ++nf) {
      size_t row = crow0 + mf * 16;
      int col = ccol0 + nf * 16;
      if (OUT_BF16) {
        unsigned short* Cp = (unsigned short*)C;
#pragma unroll
        for (int r = 0; r < 4; ++r) Cp[(row + r) * N + col] = f2bf(acc[mf][nf][r]);
      } else {
        float* Cp = (float*)C;
#pragma unroll
        for (int r = 0; r < 4; ++r) Cp[(row + r) * N + col] = acc[mf][nf][r];
      }
    }
#undef STA
#undef STB
}

// ---------------- m97-style GEMM (kept for out-proj): C[M,N] = A[M,K] * B[N,K]^T ----------------
template <bool OUT_BF16>
__global__ __launch_bounds__(256) void gemm_bt(const unsigned short* __restrict__ A,
                                               const unsigned short* __restrict__ B,
                                               void* __restrict__ C, int M, int N, int K) {
  __shared__ __align__(16) unsigned short Abuf[128 * 32];
  __shared__ __align__(16) unsigned short Bbuf[128 * 32];
  const int tid = threadIdx.x;
  const int lane = tid & 63;
  const int w = tid >> 6;
  const int wm = w >> 1, wn = w & 1;
  const int bm = blockIdx.y, bn = blockIdx.x;
  const int l15 = lane & 15, l4 = lane >> 4;

  f32x4 acc[4][4] = {};
  const int nk = K >> 5;
  for (int kk = 0; kk < nk; ++kk) {
    __syncthreads();
#pragma unroll
    for (int i = 0; i < 2; ++i) {
      int b = (w * 2 + i) * 64 + lane;
      int r = b >> 2, c = b & 3;
      int csw = c ^ (r & 3);
      gl_lds16(A + (size_t)(bm * 128 + r) * K + kk * 32 + csw * 8, &Abuf[(w * 2 + i) * 512]);
    }
#pragma unroll
    for (int i = 0; i < 2; ++i) {
      int b = (w * 2 + i) * 64 + lane;
      int r = b >> 2, c = b & 3;
      int csw = c ^ (r & 3);
      gl_lds16(B + (size_t)(bn * 128 + r) * K + kk * 32 + csw * 8, &Bbuf[(w * 2 + i) * 512]);
    }
    __syncthreads();

    bf16x8 a[4], bfr[4];
#pragma unroll
    for (int mt = 0; mt < 4; ++mt) {
      int r = wm * 64 + mt * 16 + l15;
      a[mt] = *(const bf16x8*)&Abuf[r * 32 + ((l4 ^ (r & 3)) * 8)];
    }
#pragma unroll
    for (int nt = 0; nt < 4; ++nt) {
      int r = wn * 64 + nt * 16 + l15;
      bfr[nt] = *(const bf16x8*)&Bbuf[r * 32 + ((l4 ^ (r & 3)) * 8)];
    }
#pragma unroll
    for (int mt = 0; mt < 4; ++mt)
#pragma unroll
      for (int nt = 0; nt < 4; ++nt)
        acc[mt][nt] = __builtin_amdgcn_mfma_f32_16x16x32_bf16(a[mt], bfr[nt], acc[mt][nt], 0, 0, 0);
  }

#pragma unroll
  for (int mt = 0; mt < 4; ++mt)
#pragma unroll
    for (int nt = 0; nt < 4; ++nt) {
      int row = bm * 128 + wm * 64 + mt * 16 + l4 * 4;
      int col = bn * 128 + wn * 64 + nt * 16 + l15;
      if (OUT_BF16) {
        unsigned short* Cp = (unsigned short*)C;
#pragma unroll
        for (int r = 0; r < 4; ++r) Cp[(size_t)(row + r) * N + col] = f2bf(acc[mt][nt][r]);
      } else {
        float* Cp = (float*)C;
#pragma unroll
        for (int r = 0; r < 4; ++r) Cp[(size_t)(row + r) * N + col] = acc[mt][nt][r];
      }
    }
}

// ---------------- RoPE in-place on qkv cols [0, 8192) ----------------
__global__ __launch_bounds__(256) void rope_apply(unsigned short* __restrict__ qkv,
                                                  const float* __restrict__ cs) {
  int t = blockIdx.x * blockDim.x + threadIdx.x;  // S * 8192 / 8
  if (t >= S_LEN * 1024) return;
  int row = t >> 10;
  int col = (t & 1023) * 8;
  int d = col & (HDIM - 1);
  ushort4* p = (ushort4*)(qkv + (size_t)row * QKV_LD + col);
  ushort4 v0 = p[0], v1 = p[1];
  float4 c0 = *(const float4*)&cs[row * HDIM + d];
  float4 c1 = *(const float4*)&cs[row * HDIM + d + 4];
  ushort4 o0, o1;
  {
    float t0 = bf2f(v0.x), t1 = bf2f(v0.y);
    o0.x = f2bf(t0 * c0.x - t1 * c0.y);
    o0.y = f2bf(t0 * c0.y + t1 * c0.x);
    t0 = bf2f(v0.z); t1 = bf2f(v0.w);
    o0.z = f2bf(t0 * c0.z - t1 * c0.w);
    o0.w = f2bf(t0 * c0.w + t1 * c0.z);
    t0 = bf2f(v1.x); t1 = bf2f(v1.y);
    o1.x = f2bf(t0 * c1.x - t1 * c1.y);
    o1.y = f2bf(t0 * c1.y + t1 * c1.x);
    t0 = bf2f(v1.z); t1 = bf2f(v1.w);
    o1.z = f2bf(t0 * c1.z - t1 * c1.w);
    o1.w = f2bf(t0 * c1.w + t1 * c1.z);
  }
  p[0] = o0; p[1] = o1;
}

// ---------------- V transpose: qkv cols [8192,12288) -> vt[h][d][s] ----------------
__global__ __launch_bounds__(256) void v_transpose(const unsigned short* __restrict__ qkv,
                                                   unsigned short* __restrict__ vt) {
  __shared__ unsigned short T[64][68];
  int sb = blockIdx.x * 64;
  int h = blockIdx.y >> 1;
  int d0 = (blockIdx.y & 1) * 64;
  int tid = threadIdx.x;
#pragma unroll
  for (int i = 0; i < 2; ++i) {
    int b = i * 256 + tid;
    int r = b >> 3, c = b & 7;
    const ushort4* src = (const ushort4*)(qkv + (size_t)(sb + r) * QKV_LD + 8192 + h * HDIM + d0 + c * 8);
    ushort4 a0 = src[0], a1 = src[1];
    *(ushort4*)&T[r][c * 8] = a0;
    *(ushort4*)&T[r][c * 8 + 4] = a1;
  }
  __syncthreads();
#pragma unroll
  for (int i = 0; i < 2; ++i) {
    int b = i * 256 + tid;
    int dd = b >> 3, sc = b & 7;
    unsigned short tmp[8];
#pragma unroll
    for (int j = 0; j < 8; ++j) tmp[j] = T[sc * 8 + j][dd];
    unsigned short* dst = vt + (size_t)(h * HDIM + d0 + dd) * S_LEN + sb + sc * 8;
    ushort4 lo = make_ushort4(tmp[0], tmp[1], tmp[2], tmp[3]);
    ushort4 hi = make_ushort4(tmp[4], tmp[5], tmp[6], tmp[7]);
    *(ushort4*)dst = lo;
    *(ushort4*)(dst + 4) = hi;
  }
}

// ---------------- flash attention (causal), 4 waves x 16 q-rows, KVBLK=64 ----------------
__global__ __launch_bounds__(256) void attn_kernel(const unsigned short* __restrict__ qkv,
                                                   const unsigned short* __restrict__ vt,
                                                   unsigned short* __restrict__ out) {
  __shared__ __align__(16) unsigned short Klds[64 * 128];
  __shared__ __align__(16) unsigned short Vtlds[128 * 64];
  __shared__ __align__(16) unsigned short Plds[4][16 * 72];
  const int tid = threadIdx.x, lane = tid & 63, w = tid >> 6;
  const int l15 = lane & 15, l4 = lane >> 4;
  const int h = blockIdx.y, bq = blockIdx.x;
  const int qw = bq * 64 + w * 16;

  bf16x8 qf[4];
#pragma unroll
  for (int ds = 0; ds < 4; ++ds)
    qf[ds] = *(const bf16x8*)&qkv[(size_t)(qw + l15) * QKV_LD + h * HDIM + ds * 32 + l4 * 8];

  f32x4 acc[8] = {};
  float m_run[4], l_run[4];
#pragma unroll
  for (int r = 0; r < 4; ++r) { m_run[r] = -1e30f; l_run[r] = 0.f; }

  const float scale = 0.08838834764831845f;
  const int nkt = bq + 1;
  for (int kt = 0; kt < nkt; ++kt) {
    const int kv0 = kt * 64;
    __syncthreads();
#pragma unroll
    for (int i = 0; i < 4; ++i) {
      int b = (w * 4 + i) * 64 + lane;
      int r = b >> 4, c = b & 15;
      gl_lds16(qkv + (size_t)(kv0 + r) * QKV_LD + 4096 + h * HDIM + ((c ^ (r & 15)) * 8),
               &Klds[(w * 4 + i) * 512]);
    }
#pragma unroll
    for (int i = 0; i < 4; ++i) {
      int b = (w * 4 + i) * 64 + lane;
      int r = b >> 3, c = b & 7;
      gl_lds16(vt + (size_t)(h * HDIM + r) * S_LEN + kv0 + ((c ^ (r & 7)) * 8),
               &Vtlds[(w * 4 + i) * 512]);
    }
    __syncthreads();

    f32x4 s[4] = {};
#pragma unroll
    for (int jt = 0; jt < 4; ++jt) {
      int kr = jt * 16 + l15;
#pragma unroll
      for (int ds = 0; ds < 4; ++ds) {
        int c = (ds * 4 + l4) ^ (kr & 15);
        bf16x8 kf = *(const bf16x8*)&Klds[kr * 128 + c * 8];
        s[jt] = __builtin_amdgcn_mfma_f32_16x16x32_bf16(qf[ds], kf, s[jt], 0, 0, 0);
      }
    }

    const bool diag = (kt == bq);
#pragma unroll
    for (int jt = 0; jt < 4; ++jt)
#pragma unroll
      for (int r = 0; r < 4; ++r) {
        float v = s[jt][r] * scale;
        if (diag) {
          int kvg = kv0 + jt * 16 + l15;
          int qg = qw + l4 * 4 + r;
          if (kvg > qg) v = -1e30f;
        }
        s[jt][r] = v;
      }

    float alpha[4];
#pragma unroll
    for (int r = 0; r < 4; ++r) {
      float mx = fmaxf(fmaxf(s[0][r], s[1][r]), fmaxf(s[2][r], s[3][r]));
#pragma unroll
      for (int off = 1; off < 16; off <<= 1) mx = fmaxf(mx, __shfl_xor(mx, off, 64));
      float mi = fmaxf(m_run[r], mx);
      alpha[r] = __expf(m_run[r] - mi);
      m_run[r] = mi;
      float sum = 0.f;
#pragma unroll
      for (int jt = 0; jt < 4; ++jt) {
        float p = __expf(s[jt][r] - mi);
        s[jt][r] = p;
        sum += p;
      }
#pragma unroll
      for (int off = 1; off < 16; off <<= 1) sum += __shfl_xor(sum, off, 64);
      l_run[r] = l_run[r] * alpha[r] + sum;
    }
#pragma unroll
    for (int dt = 0; dt < 8; ++dt)
#pragma unroll
      for (int r = 0; r < 4; ++r) acc[dt][r] *= alpha[r];

    unsigned short* P = &Plds[w][0];
#pragma unroll
    for (int jt = 0; jt < 4; ++jt)
#pragma unroll
      for (int r = 0; r < 4; ++r)
        P[(l4 * 4 + r) * 72 + jt * 16 + l15] = f2bf(s[jt][r]);

#pragma unroll
    for (int ks = 0; ks < 2; ++ks) {
      bf16x8 pa = *(const bf16x8*)&P[l15 * 72 + ks * 32 + l4 * 8];
#pragma unroll
      for (int dt = 0; dt < 8; ++dt) {
        int vr = dt * 16 + l15;
        int c = (ks * 4 + l4) ^ (vr & 7);
        bf16x8 vf = *(const bf16x8*)&Vtlds[vr * 64 + c * 8];
        acc[dt] = __builtin_amdgcn_mfma_f32_16x16x32_bf16(pa, vf, acc[dt], 0, 0, 0);
      }
    }
  }

#pragma unroll
  for (int dt = 0; dt < 8; ++dt)
#pragma unroll
    for (int r = 0; r < 4; ++r) {
      float v = acc[dt][r] / l_run[r];
      int row = qw + l4 * 4 + r;
      int col = h * HDIM + dt * 16 + l15;
      out[(size_t)row * DMODEL + col] = f2bf(v);
    }
}

// ---------------- launcher ----------------
extern "C" void kernel_launch(void* const* d_in, const int* in_sizes, int n_in,
                              void* d_out, int out_size, void* d_ws, size_t ws_size,
                              hipStream_t stream) {
  const float* x = (const float*)d_in[0];
  const float* fr = (const float*)d_in[1];
  const float* wq = (const float*)d_in[2];
  const float* wk = (const float*)d_in[3];
  const float* wv = (const float*)d_in[4];
  const float* wo = (const float*)d_in[5];

  char* ws = (char*)d_ws;
  const size_t OFF_XB   = 0;                       // 2048*4096*2      = 16 MB
  const size_t OFF_WQKV = 16777216;                // 12288*4096*2     = 96 MB
  const size_t OFF_WO   = OFF_WQKV + 100663296;    // 4096*4096*2      = 32 MB
  const size_t OFF_QKV  = OFF_WO + 33554432;       // 2048*12288*2     = 48 MB
  const size_t OFF_CS   = OFF_QKV + 50331648;      // 2048*128*4       = 1 MB
  const size_t OFF_VT   = OFF_CS + 1048576;        // 32*128*2048*2    = 16 MB
  const size_t OFF_ATTN = OFF_VT + 16777216;       // 2048*4096*2     = 16 MB

  unsigned short* xb    = (unsigned short*)(ws + OFF_XB);
  unsigned short* wqkvb = (unsigned short*)(ws + OFF_WQKV);
  unsigned short* wob   = (unsigned short*)(ws + OFF_WO);
  unsigned short* qkvb  = (unsigned short*)(ws + OFF_QKV);
  float*          cs    = (float*)(ws + OFF_CS);
  unsigned short* vt    = (unsigned short*)(ws + OFF_VT);
  unsigned short* attn  = (unsigned short*)(ws + OFF_ATTN);

  // 1. casts
  cast_f32_bf16<<<2048, 256, 0, stream>>>(x, xb, 2097152);
  cast_f32_bf16<<<2048, 256, 0, stream>>>(wq, wqkvb, 4194304);
  cast_f32_bf16<<<2048, 256, 0, stream>>>(wk, wqkvb + 16777216, 4194304);
  cast_f32_bf16<<<2048, 256, 0, stream>>>(wv, wqkvb + 33554432, 4194304);
  cast_f32_bf16<<<2048, 256, 0, stream>>>(wo, wob, 4194304);
  // 2. rope table
  rope_table<<<512, 256, 0, stream>>>(fr, cs);
  // 3. fused QKV projection (256^2 8-phase): grid = (2048/256)*(12288/256) = 384
  gemm256_8ph<true><<<dim3(384), 512, 0, stream>>>(xb, wqkvb, qkvb, 2048, 12288, 4096);
  // 4. RoPE on q,k
  rope_apply<<<8192, 256, 0, stream>>>(qkvb, cs);
  // 5. V transpose
  v_transpose<<<dim3(32, 64), 256, 0, stream>>>(qkvb, vt);
  // 6. flash attention
  attn_kernel<<<dim3(32, 32), 256, 0, stream>>>(qkvb, vt, attn);
  // 7. output projection (fp32 out)
  gemm_bt<false><<<dim3(32, 16), 256, 0, stream>>>(attn, wob, d_out, 2048, 4096, 4096);
}